// Round 1
// baseline (1517.543 us; speedup 1.0000x reference)
//
#include <hip/hip_runtime.h>
#include <cmath>

#define SEQ 32
#define BB 1024
#define II 2048
#define OO 1024

typedef unsigned short ushortt;
typedef short v8s __attribute__((ext_vector_type(8)));
typedef float v4f __attribute__((ext_vector_type(4)));

// ---------------- init: zero a float4 region ----------------
__global__ void zero_kernel(float4* __restrict__ p, int n4) {
  int i = blockIdx.x * blockDim.x + threadIdx.x;
  int stride = gridDim.x * blockDim.x;
  float4 z; z.x = z.y = z.z = z.w = 0.f;
  for (; i < n4; i += stride) p[i] = z;
}

// ---------------- fp32 transpose: dst[c*R+r] = src[r*C+c] ----------------
__global__ void transpose_f32(const float* __restrict__ src, float* __restrict__ dst,
                              int R, int C) {
  __shared__ float t[32][33];
  int c0 = blockIdx.x * 32, r0 = blockIdx.y * 32;
  int tx = threadIdx.x, ty = threadIdx.y;
#pragma unroll
  for (int k = 0; k < 4; k++)
    t[ty + k * 8][tx] = src[(long)(r0 + ty + k * 8) * C + c0 + tx];
  __syncthreads();
#pragma unroll
  for (int k = 0; k < 4; k++)
    dst[(long)(c0 + ty + k * 8) * R + r0 + tx] = t[tx][ty + k * 8];
}

// ---------------- x prep: xT bf16 [I][B] + column counts n[i] ----------------
__global__ void prep_x(const float* __restrict__ x, ushortt* __restrict__ xT,
                       float* __restrict__ nvec) {
  __shared__ ushortt t[32][33];
  int i0 = blockIdx.x * 32, b0 = blockIdx.y * 32;
  int tx = threadIdx.x, ty = threadIdx.y;
#pragma unroll
  for (int k = 0; k < 4; k++) {
    float val = x[(long)(b0 + ty + k * 8) * II + i0 + tx];
    ushortt us = (val != 0.0f) ? (ushortt)0x3F80 : (ushortt)0;  // bf16 1.0
    t[ty + k * 8][tx] = us;
    if (us) atomicAdd(&nvec[i0 + tx], 1.0f);  // exact integer counts in fp32
  }
  __syncthreads();
#pragma unroll
  for (int k = 0; k < 4; k++)
    xT[(long)(i0 + ty + k * 8) * BB + b0 + tx] = t[tx][ty + k * 8];
}

// ---------------- per-row active-index lists (ordered, deterministic) ----------------
__global__ void build_idx(const float* __restrict__ x, ushortt* __restrict__ idxArr,
                          int* __restrict__ cntArr) {
  int b = blockIdx.x;
  int lane = threadIdx.x;  // 64 threads = 1 wave
  const float* row = x + (long)b * II;
  int base = 0;
  for (int c = 0; c < II / 64; ++c) {
    float val = row[c * 64 + lane];
    unsigned long long m = __ballot(val != 0.0f);
    if (val != 0.0f) {
      int pos = base + __popcll(m & ((1ull << lane) - 1ull));
      if (pos < 256) idxArr[(b << 8) + pos] = (ushortt)(c * 64 + lane);
    }
    base += __popcll(m);
  }
  if (lane == 0) cntArr[b] = base < 256 ? base : 256;
}

// ---------------- K1: z_in gather + LIF + zT + column spike counts ----------------
__global__ __launch_bounds__(256) void step_kernel(
    const float* __restrict__ wT, const float* __restrict__ bias,
    const ushortt* __restrict__ idxArr, const int* __restrict__ cntArr,
    float* __restrict__ v, ushortt* __restrict__ zT, float* __restrict__ cvec,
    float vd, int last, float* __restrict__ outz, float* __restrict__ outv) {
  int b = blockIdx.x, tid = threadIdx.x;
  __shared__ ushortt sIdx[256];
  sIdx[tid] = idxArr[(b << 8) + tid];
  __syncthreads();
  int cnt = cntArr[b];
  const float4* wT4 = (const float4*)wT;  // wT row = 256 float4
  float4 acc; acc.x = acc.y = acc.z = acc.w = 0.f;
  int j = 0;
  for (; j + 4 <= cnt; j += 4) {
    int i0 = sIdx[j], i1 = sIdx[j + 1], i2 = sIdx[j + 2], i3 = sIdx[j + 3];
    float4 a0 = wT4[(i0 << 8) + tid];
    float4 a1 = wT4[(i1 << 8) + tid];
    float4 a2 = wT4[(i2 << 8) + tid];
    float4 a3 = wT4[(i3 << 8) + tid];
    acc.x += a0.x; acc.y += a0.y; acc.z += a0.z; acc.w += a0.w;
    acc.x += a1.x; acc.y += a1.y; acc.z += a1.z; acc.w += a1.w;
    acc.x += a2.x; acc.y += a2.y; acc.z += a2.z; acc.w += a2.w;
    acc.x += a3.x; acc.y += a3.y; acc.z += a3.z; acc.w += a3.w;
  }
  for (; j < cnt; ++j) {
    float4 a = wT4[((int)sIdx[j] << 8) + tid];
    acc.x += a.x; acc.y += a.y; acc.z += a.z; acc.w += a.w;
  }
  float4 bi = ((const float4*)bias)[tid];
  float4 vv = ((const float4*)v)[(b << 8) + tid];
  float zin[4] = {acc.x + bi.x, acc.y + bi.y, acc.z + bi.z, acc.w + bi.w};
  float vr[4] = {vv.x, vv.y, vv.z, vv.w};
  float zo[4];
#pragma unroll
  for (int c2 = 0; c2 < 4; c2++) {
    float nv = vr[c2] * vd + zin[c2];
    float z = (nv >= 1.0f) ? 1.0f : 0.0f;
    nv = nv * (1.0f - z);
    vr[c2] = nv; zo[c2] = z;
    int o = (tid << 2) + c2;
    zT[(o << 10) + b] = (z != 0.f) ? (ushortt)0x3F80 : (ushortt)0;
    if (z != 0.f) atomicAdd(&cvec[o], 1.0f);  // exact integer counts
  }
  float4 vout; vout.x = vr[0]; vout.y = vr[1]; vout.z = vr[2]; vout.w = vr[3];
  ((float4*)v)[(b << 8) + tid] = vout;
  if (last) {
    float4 zout; zout.x = zo[0]; zout.y = zo[1]; zout.z = zo[2]; zout.w = zo[3];
    ((float4*)outz)[(b << 8) + tid] = zout;
    ((float4*)outv)[(b << 8) + tid] = vout;
  }
}

// ---------------- K3: MT = x^T z (bf16 MFMA, exact) fused with A/w update ----------------
// MT[i,o]; A_t = d*A + MT; wT[i,o] = clip(wT + 1e-3*(pt*c[o] + spre*MT) - 1e-3*(pt*n[i] + A_t))
__global__ __launch_bounds__(256) void stdp_kernel(
    const ushortt* __restrict__ xT, const ushortt* __restrict__ zT,
    const float* __restrict__ cvec, const float* __restrict__ nvec,
    float* __restrict__ wT, float* __restrict__ AT,
    float d, float pt, float spre) {
  int bi0 = blockIdx.x * 64;  // i tile (32 blocks)
  int bo0 = blockIdx.y * 64;  // o tile (16 blocks)
  int tid = threadIdx.x, lane = tid & 63, wv = tid >> 6;
  __shared__ float sC[64];
  __shared__ int sFlag;
  __shared__ ushortt As[64 * 40];  // 64 i-rows x 32 k, pad to 40 shorts
  __shared__ ushortt Bs[64 * 40];  // 64 o-rows x 32 k
  if (tid < 64) sC[tid] = cvec[bo0 + tid];
  if (tid == 0) sFlag = 0;
  __syncthreads();
  if (tid < 64 && sC[tid] != 0.0f) sFlag = 1;
  __syncthreads();

  v4f acc0 = {0.f, 0.f, 0.f, 0.f}, acc1 = acc0, acc2 = acc0, acc3 = acc0;
  if (sFlag) {
    int arow = tid >> 2, aoct = (tid & 3) * 8;
    int fr = (lane & 15), foct = (lane >> 4) * 8;
    for (int kc = 0; kc < BB; kc += 32) {
      *(uint4*)&As[arow * 40 + aoct] = *(const uint4*)&xT[(long)(bi0 + arow) * BB + kc + aoct];
      *(uint4*)&Bs[arow * 40 + aoct] = *(const uint4*)&zT[(long)(bo0 + arow) * BB + kc + aoct];
      __syncthreads();
      v8s af = *(const v8s*)&As[(wv * 16 + fr) * 40 + foct];
      acc0 = __builtin_amdgcn_mfma_f32_16x16x32_bf16(af, *(const v8s*)&Bs[(0 + fr) * 40 + foct], acc0, 0, 0, 0);
      acc1 = __builtin_amdgcn_mfma_f32_16x16x32_bf16(af, *(const v8s*)&Bs[(16 + fr) * 40 + foct], acc1, 0, 0, 0);
      acc2 = __builtin_amdgcn_mfma_f32_16x16x32_bf16(af, *(const v8s*)&Bs[(32 + fr) * 40 + foct], acc2, 0, 0, 0);
      acc3 = __builtin_amdgcn_mfma_f32_16x16x32_bf16(af, *(const v8s*)&Bs[(48 + fr) * 40 + foct], acc3, 0, 0, 0);
      __syncthreads();
    }
  }
  // epilogue: C layout col=lane&15, row=(lane>>4)*4+reg
  int col = lane & 15;
  int r0 = (lane >> 4) * 4;
  float ni[4];
#pragma unroll
  for (int reg = 0; reg < 4; reg++) ni[reg] = nvec[bi0 + wv * 16 + r0 + reg];
  v4f accs[4] = {acc0, acc1, acc2, acc3};
#pragma unroll
  for (int ot = 0; ot < 4; ot++) {
    int o = bo0 + ot * 16 + col;
    float cv = sC[ot * 16 + col];
#pragma unroll
    for (int reg = 0; reg < 4; reg++) {
      int i = bi0 + wv * 16 + r0 + reg;
      int idx = i * OO + o;
      float mt = accs[ot][reg];
      float at = AT[idx];
      float atn = d * at + mt;
      AT[idx] = atn;
      float wval = wT[idx];
      float dw = 1e-3f * (pt * cv + spre * mt) - 1e-3f * (pt * ni[reg] + atn);
      wval += dw;
      wval = fminf(fmaxf(wval, -1.0f), 1.0f);
      wT[idx] = wval;
    }
  }
}

extern "C" void kernel_launch(void* const* d_in, const int* in_sizes, int n_in,
                              void* d_out, int out_size, void* d_ws, size_t ws_size,
                              hipStream_t stream) {
  const float* x = (const float*)d_in[0];     // [B, I] {0,1} fp32
  const float* w = (const float*)d_in[1];     // [O, I] fp32
  const float* bias = (const float*)d_in[2];  // [O]
  float* out = (float*)d_out;                 // z[B,O] | v[B,O] | w[O,I]

  char* ws = (char*)d_ws;
  float* wT = (float*)(ws + 0);                    // [I][O] 8 MB
  float* AT = (float*)(ws + 8388608);              // [I][O] 8 MB
  float* vbuf = (float*)(ws + 16777216);           // [B][O] 4 MB
  float* cbuf = (float*)(ws + 20971520);           // [32][O] 128 KB
  float* nvec = (float*)(ws + 21102592);           // [I] 8 KB
  int* cntArr = (int*)(ws + 21110784);             // [B] 4 KB
  ushortt* idxArr = (ushortt*)(ws + 21114880);     // [B][256] 512 KB
  ushortt* zT = (ushortt*)(ws + 21639168);         // [O][B] bf16 2 MB
  ushortt* xT = (ushortt*)(ws + 23736320);         // [I][B] bf16 4 MB

  // zero AT, v, c, n, cnt (contiguous region: 8388608 .. 21114880 = 12726272 B)
  zero_kernel<<<1024, 256, 0, stream>>>((float4*)(ws + 8388608), 12726272 / 16);
  // wT = w^T
  transpose_f32<<<dim3(II / 32, OO / 32), dim3(32, 8), 0, stream>>>(w, wT, OO, II);
  // xT bf16 + n
  prep_x<<<dim3(II / 32, BB / 32), dim3(32, 8), 0, stream>>>(x, xT, nvec);
  // active index lists
  build_idx<<<BB, 64, 0, stream>>>(x, idxArr, cntArr);

  const float dec = (float)exp(-0.05);  // decay (same for pre/post/mem)
  float p = 1.0f, u = 1.0f;             // tpre values for x=0 / x=1 (fp32 recurrence, matches np)
  for (int t = 0; t < SEQ; ++t) {
    p = p * dec;
    u = u * dec;
    u = u + 1.0f;
    float spre = u - p;
    int last = (t == SEQ - 1) ? 1 : 0;
    step_kernel<<<BB, 256, 0, stream>>>(wT, bias, idxArr, cntArr, vbuf, zT,
                                        cbuf + t * OO, dec, last,
                                        out, out + BB * OO);
    stdp_kernel<<<dim3(II / 64, OO / 64), 256, 0, stream>>>(xT, zT, cbuf + t * OO,
                                                            nvec, wT, AT, dec, p, spre);
  }
  // final w = wT^T -> d_out[2M..4M)
  transpose_f32<<<dim3(OO / 32, II / 32), dim3(32, 8), 0, stream>>>(wT, out + 2 * BB * OO, II, OO);
}

// Round 3
// 1460.734 us; speedup vs baseline: 1.0389x; 1.0389x over previous
//
#include <hip/hip_runtime.h>
#include <cmath>

#define SEQ 32
#define BB 1024
#define II 2048
#define OO 1024

typedef unsigned short ushortt;
typedef short v8s __attribute__((ext_vector_type(8)));
typedef float v4f __attribute__((ext_vector_type(4)));

// ---------------- init: zero a float4 region ----------------
__global__ void zero_kernel(float4* __restrict__ p, int n4) {
  int i = blockIdx.x * blockDim.x + threadIdx.x;
  int stride = gridDim.x * blockDim.x;
  float4 z; z.x = z.y = z.z = z.w = 0.f;
  for (; i < n4; i += stride) p[i] = z;
}

// ---------------- fp32 transpose: dst[c*R+r] = src[r*C+c] ----------------
__global__ void transpose_f32(const float* __restrict__ src, float* __restrict__ dst,
                              int R, int C) {
  __shared__ float t[32][33];
  int c0 = blockIdx.x * 32, r0 = blockIdx.y * 32;
  int tx = threadIdx.x, ty = threadIdx.y;
#pragma unroll
  for (int k = 0; k < 4; k++)
    t[ty + k * 8][tx] = src[(long)(r0 + ty + k * 8) * C + c0 + tx];
  __syncthreads();
#pragma unroll
  for (int k = 0; k < 4; k++)
    dst[(long)(c0 + ty + k * 8) * R + r0 + tx] = t[tx][ty + k * 8];
}

// ---------------- x prep: xT bf16 [I][B] + column counts n[i] ----------------
__global__ void prep_x(const float* __restrict__ x, ushortt* __restrict__ xT,
                       float* __restrict__ nvec) {
  __shared__ ushortt t[32][33];
  int i0 = blockIdx.x * 32, b0 = blockIdx.y * 32;
  int tx = threadIdx.x, ty = threadIdx.y;
#pragma unroll
  for (int k = 0; k < 4; k++) {
    float val = x[(long)(b0 + ty + k * 8) * II + i0 + tx];
    ushortt us = (val != 0.0f) ? (ushortt)0x3F80 : (ushortt)0;  // bf16 1.0
    t[ty + k * 8][tx] = us;
    if (us) atomicAdd(&nvec[i0 + tx], 1.0f);  // exact integer counts in fp32
  }
  __syncthreads();
#pragma unroll
  for (int k = 0; k < 4; k++)
    xT[(long)(i0 + ty + k * 8) * BB + b0 + tx] = t[tx][ty + k * 8];
}

// ---------------- per-row active-index lists (ordered, deterministic) ----------------
__global__ void build_idx(const float* __restrict__ x, ushortt* __restrict__ idxArr,
                          int* __restrict__ cntArr) {
  int b = blockIdx.x;
  int lane = threadIdx.x;  // 64 threads = 1 wave
  const float* row = x + (long)b * II;
  int base = 0;
  for (int c = 0; c < II / 64; ++c) {
    float val = row[c * 64 + lane];
    unsigned long long m = __ballot(val != 0.0f);
    if (val != 0.0f) {
      int pos = base + __popcll(m & ((1ull << lane) - 1ull));
      if (pos < 256) idxArr[(b << 8) + pos] = (ushortt)(c * 64 + lane);
    }
    base += __popcll(m);
  }
  if (lane == 0) cntArr[b] = base < 256 ? base : 256;
}

// ---------------- K1: z_in gather + LIF + zT + column spike counts ----------------
__global__ __launch_bounds__(256) void step_kernel(
    const float* __restrict__ wT, const float* __restrict__ bias,
    const ushortt* __restrict__ idxArr, const int* __restrict__ cntArr,
    float* __restrict__ v, ushortt* __restrict__ zT, float* __restrict__ cvec,
    float vd, int last, float* __restrict__ outz, float* __restrict__ outv) {
  int b = blockIdx.x, tid = threadIdx.x;
  __shared__ ushortt sIdx[256];
  sIdx[tid] = idxArr[(b << 8) + tid];
  __syncthreads();
  int cnt = cntArr[b];
  const float4* wT4 = (const float4*)wT;  // wT row = 256 float4
  float4 acc; acc.x = acc.y = acc.z = acc.w = 0.f;
  int j = 0;
  for (; j + 4 <= cnt; j += 4) {
    int i0 = sIdx[j], i1 = sIdx[j + 1], i2 = sIdx[j + 2], i3 = sIdx[j + 3];
    float4 a0 = wT4[(i0 << 8) + tid];
    float4 a1 = wT4[(i1 << 8) + tid];
    float4 a2 = wT4[(i2 << 8) + tid];
    float4 a3 = wT4[(i3 << 8) + tid];
    acc.x += a0.x; acc.y += a0.y; acc.z += a0.z; acc.w += a0.w;
    acc.x += a1.x; acc.y += a1.y; acc.z += a1.z; acc.w += a1.w;
    acc.x += a2.x; acc.y += a2.y; acc.z += a2.z; acc.w += a2.w;
    acc.x += a3.x; acc.y += a3.y; acc.z += a3.z; acc.w += a3.w;
  }
  for (; j < cnt; ++j) {
    float4 a = wT4[((int)sIdx[j] << 8) + tid];
    acc.x += a.x; acc.y += a.y; acc.z += a.z; acc.w += a.w;
  }
  float4 bi = ((const float4*)bias)[tid];
  float4 vv = ((const float4*)v)[(b << 8) + tid];
  float zin[4] = {acc.x + bi.x, acc.y + bi.y, acc.z + bi.z, acc.w + bi.w};
  float vr[4] = {vv.x, vv.y, vv.z, vv.w};
  float zo[4];
#pragma unroll
  for (int c2 = 0; c2 < 4; c2++) {
    float nv = vr[c2] * vd + zin[c2];
    float z = (nv >= 1.0f) ? 1.0f : 0.0f;
    nv = nv * (1.0f - z);
    vr[c2] = nv; zo[c2] = z;
    int o = (tid << 2) + c2;
    zT[(o << 10) + b] = (z != 0.f) ? (ushortt)0x3F80 : (ushortt)0;
    if (z != 0.f) atomicAdd(&cvec[o], 1.0f);  // exact integer counts
  }
  float4 vout; vout.x = vr[0]; vout.y = vr[1]; vout.z = vr[2]; vout.w = vr[3];
  ((float4*)v)[(b << 8) + tid] = vout;
  if (last) {
    float4 zout; zout.x = zo[0]; zout.y = zo[1]; zout.z = zo[2]; zout.w = zo[3];
    ((float4*)outz)[(b << 8) + tid] = zout;
    ((float4*)outv)[(b << 8) + tid] = vout;
  }
}

// ---------------- K3 eager: MT = x^T z (bf16 MFMA, exact) + coalesced A/w RMW ----------------
// MT[i,o]; A_t = d*A + MT; wT[i,o] = clip(wT + 1e-3*(pt*c[o] + spre*MT) - 1e-3*(pt*n[i] + A_t))
__global__ __launch_bounds__(256) void stdp_kernel(
    const ushortt* __restrict__ xT, const ushortt* __restrict__ zT,
    const float* __restrict__ cvec, const float* __restrict__ nvec,
    float* __restrict__ wT, float* __restrict__ AT,
    float dec, float pt, float spre) {
  int bi0 = blockIdx.x * 64;  // i tile (32 blocks)
  int bo0 = blockIdx.y * 64;  // o tile (16 blocks)
  int tid = threadIdx.x, lane = tid & 63, wv = tid >> 6;
  __shared__ float sC[64];
  __shared__ float sN[64];
  __shared__ int sFlag;
  __shared__ ushortt As[64 * 72];  // 64 i-rows x 64 k (pad 72, 16B-aligned rows)
  __shared__ ushortt Bs[64 * 72];  // 64 o-rows x 64 k
  __shared__ float Ms[64 * 68];    // M tile, [i][o], pad 68
  if (tid < 64) { sC[tid] = cvec[bo0 + tid]; sN[tid] = nvec[bi0 + tid]; }
  if (tid == 0) sFlag = 0;
  __syncthreads();
  if (tid < 64 && sC[tid] != 0.0f) sFlag = 1;
  __syncthreads();
  int spike = sFlag;

  if (spike) {
    v4f acc0 = {0.f, 0.f, 0.f, 0.f}, acc1 = acc0, acc2 = acc0, acc3 = acc0;
    int arow = tid >> 2, acol = (tid & 3) * 16;
    int fr = lane & 15, foct = (lane >> 4) * 8;
    for (int kc = 0; kc < BB; kc += 64) {
      *(uint4*)&As[arow * 72 + acol]     = *(const uint4*)&xT[(long)(bi0 + arow) * BB + kc + acol];
      *(uint4*)&As[arow * 72 + acol + 8] = *(const uint4*)&xT[(long)(bi0 + arow) * BB + kc + acol + 8];
      *(uint4*)&Bs[arow * 72 + acol]     = *(const uint4*)&zT[(long)(bo0 + arow) * BB + kc + acol];
      *(uint4*)&Bs[arow * 72 + acol + 8] = *(const uint4*)&zT[(long)(bo0 + arow) * BB + kc + acol + 8];
      __syncthreads();
#pragma unroll
      for (int ks = 0; ks < 64; ks += 32) {
        v8s af = *(const v8s*)&As[(wv * 16 + fr) * 72 + ks + foct];
        acc0 = __builtin_amdgcn_mfma_f32_16x16x32_bf16(af, *(const v8s*)&Bs[(0 + fr) * 72 + ks + foct], acc0, 0, 0, 0);
        acc1 = __builtin_amdgcn_mfma_f32_16x16x32_bf16(af, *(const v8s*)&Bs[(16 + fr) * 72 + ks + foct], acc1, 0, 0, 0);
        acc2 = __builtin_amdgcn_mfma_f32_16x16x32_bf16(af, *(const v8s*)&Bs[(32 + fr) * 72 + ks + foct], acc2, 0, 0, 0);
        acc3 = __builtin_amdgcn_mfma_f32_16x16x32_bf16(af, *(const v8s*)&Bs[(48 + fr) * 72 + ks + foct], acc3, 0, 0, 0);
      }
      __syncthreads();
    }
    // stage M to LDS: C layout col=lane&15, row=(lane>>4)*4+reg
    int col = lane & 15;
    int r0 = (lane >> 4) * 4;
    v4f accs[4] = {acc0, acc1, acc2, acc3};
#pragma unroll
    for (int ot = 0; ot < 4; ot++)
#pragma unroll
      for (int reg = 0; reg < 4; reg++)
        Ms[(wv * 16 + r0 + reg) * 68 + ot * 16 + col] = accs[ot][reg];
  }
  __syncthreads();

  // coalesced epilogue: thread -> (row r, float4 group c4)
#pragma unroll
  for (int p = 0; p < 4; p++) {
    int r = p * 16 + (tid >> 4);
    int c4 = tid & 15;
    long base = (long)(bi0 + r) * OO + bo0 + c4 * 4;
    float4 a4 = *(float4*)&AT[base];
    float4 w4 = *(float4*)&wT[base];
    float ni = sN[r];
    float m[4];
    if (spike) {
#pragma unroll
      for (int k = 0; k < 4; k++) m[k] = Ms[r * 68 + c4 * 4 + k];
    } else {
#pragma unroll
      for (int k = 0; k < 4; k++) m[k] = 0.0f;
    }
    float* ap = &a4.x;
    float* wp = &w4.x;
#pragma unroll
    for (int k = 0; k < 4; k++) {
      float cv = sC[c4 * 4 + k];
      float atn = dec * ap[k] + m[k];
      float dw = 1e-3f * (pt * cv + spre * m[k]) - 1e-3f * (pt * ni + atn);
      float wval = fminf(fmaxf(wp[k] + dw, -1.0f), 1.0f);
      ap[k] = atn;
      wp[k] = wval;
    }
    *(float4*)&AT[base] = a4;
    *(float4*)&wT[base] = w4;
  }
}

extern "C" void kernel_launch(void* const* d_in, const int* in_sizes, int n_in,
                              void* d_out, int out_size, void* d_ws, size_t ws_size,
                              hipStream_t stream) {
  const float* x = (const float*)d_in[0];     // [B, I] {0,1} fp32
  const float* w = (const float*)d_in[1];     // [O, I] fp32
  const float* bias = (const float*)d_in[2];  // [O]
  float* out = (float*)d_out;                 // z[B,O] | v[B,O] | w[O,I]

  char* ws = (char*)d_ws;
  float* wT = (float*)(ws + 0);                    // [I][O] 8 MB
  float* AT = (float*)(ws + 8388608);              // [I][O] 8 MB
  float* vbuf = (float*)(ws + 16777216);           // [B][O] 4 MB
  float* cbuf = (float*)(ws + 20971520);           // [32][O] 128 KB
  float* nvec = (float*)(ws + 21102592);           // [I] 8 KB
  int* cntArr = (int*)(ws + 21110784);             // [B] 4 KB
  ushortt* idxArr = (ushortt*)(ws + 21114880);     // [B][256] 512 KB
  ushortt* zT = (ushortt*)(ws + 21639168);         // [O][B] bf16 2 MB
  ushortt* xT = (ushortt*)(ws + 23736320);         // [I][B] bf16 4 MB

  // zero AT, v, c, n, cnt (contiguous region: 8388608 .. 21114880 = 12726272 B)
  zero_kernel<<<1024, 256, 0, stream>>>((float4*)(ws + 8388608), 12726272 / 16);
  // wT = w^T
  transpose_f32<<<dim3(II / 32, OO / 32), dim3(32, 8), 0, stream>>>(w, wT, OO, II);
  // xT bf16 + n
  prep_x<<<dim3(II / 32, BB / 32), dim3(32, 8), 0, stream>>>(x, xT, nvec);
  // active index lists
  build_idx<<<BB, 64, 0, stream>>>(x, idxArr, cntArr);

  const float dec = (float)exp(-0.05);  // decay (same for pre/post/mem)
  float p = 1.0f, u = 1.0f;             // tpre values for x=0 / x=1 (fp32 recurrence, matches np)
  for (int t = 0; t < SEQ; ++t) {
    p = p * dec;
    u = u * dec;
    u = u + 1.0f;
    float spre = u - p;
    int last = (t == SEQ - 1) ? 1 : 0;
    step_kernel<<<BB, 256, 0, stream>>>(wT, bias, idxArr, cntArr, vbuf, zT,
                                        cbuf + t * OO, dec, last,
                                        out, out + BB * OO);
    stdp_kernel<<<dim3(II / 64, OO / 64), 256, 0, stream>>>(xT, zT, cbuf + t * OO,
                                                            nvec, wT, AT, dec, p, spre);
  }
  // final w = wT^T -> d_out[2M..4M)
  transpose_f32<<<dim3(OO / 32, II / 32), dim3(32, 8), 0, stream>>>(wT, out + 2 * BB * OO, II, OO);
}